// Round 8
// baseline (161.798 us; speedup 1.0000x reference)
//
#include <hip/hip_runtime.h>
#include <hip/hip_bf16.h>
#include <hip/hip_fp16.h>
#include <stdint.h>

// deform_conv2d: N=8, C=256, H=W=64, OC=256, 3x3, stride=1, pad=1 -> OH=OW=64
// im2col-fused MFMA GEMM. M=32768 (n,oh,ow), N=256 oc, K=2304 (kd = k*256+c).
// R7: register software-pipeline -- corners for chunk t+2 prefetched into VGPRs
//     at body t (weights latched), e-coords refreshed one tap ahead; phase 2 is
//     interp(regs)->ds_write + BDMA + MFMA with no serial L2 chain. Single
//     At/Bt (preloads make them safe). Preps merged into one kernel.

typedef short short8 __attribute__((ext_vector_type(8)));
typedef float f32x4 __attribute__((ext_vector_type(4)));

__device__ __forceinline__ float bflo(uint32_t u) { return __uint_as_float(u << 16); }
__device__ __forceinline__ float bfhi(uint32_t u) { return __uint_as_float(u & 0xffff0000u); }
__device__ __forceinline__ uint32_t packbf(float a, float b) {
  unsigned short ua = __builtin_bit_cast(unsigned short, __float2bfloat16(a));
  unsigned short ub = __builtin_bit_cast(unsigned short, __float2bfloat16(b));
  return (uint32_t)ua | ((uint32_t)ub << 16);
}
__device__ __forceinline__ float h2f(uint32_t bits16) {
  __half h = __builtin_bit_cast(__half, (unsigned short)bits16);
  return __half2float(h);
}

// ---- merged prep: [0,2048) x transpose; [2048,4352) weights; [4352,5504) coords ----
__global__ __launch_bounds__(256) void prep_all_kernel(const float* __restrict__ x,
                                                       const float* __restrict__ w,
                                                       const float* __restrict__ offset,
                                                       unsigned short* __restrict__ xb,
                                                       unsigned short* __restrict__ w3s,
                                                       unsigned short* __restrict__ coords) {
  __shared__ float tile[64][65];
  int tid = threadIdx.x;
  if (blockIdx.x < 2048) {
    // x NCHW fp32 -> NHWC bf16
    int bn   = blockIdx.x >> 8;
    int rem  = blockIdx.x & 255;
    int y    = rem >> 2;
    int cblk = rem & 3;
    const float* src = x + ((size_t)(bn * 256 + cblk * 64)) * 4096 + y * 64;
#pragma unroll
    for (int i = 0; i < 4; ++i) {
      int u  = i * 256 + tid;
      int cl = u >> 4;
      int xs = (u & 15) * 4;
      float4 v = *(const float4*)(src + cl * 4096 + xs);
      tile[cl][xs] = v.x; tile[cl][xs + 1] = v.y;
      tile[cl][xs + 2] = v.z; tile[cl][xs + 3] = v.w;
    }
    __syncthreads();
    unsigned short* dst = xb + ((size_t)(bn * 64 + y) * 64) * 256 + cblk * 64;
#pragma unroll
    for (int i = 0; i < 8; ++i) {
      int v2  = i * 256 + tid;
      int xc  = v2 >> 5;
      int cl2 = (v2 & 31) * 2;
      *(uint32_t*)(dst + xc * 256 + cl2) = packbf(tile[cl2][xc], tile[cl2 + 1][xc]);
    }
  } else if (blockIdx.x < 4352) {
    // weights -> XOR-swizzled chunk-major bf16 image
    int idx = (blockIdx.x - 2048) * 256 + tid;   // < 589824
    int t   = idx >> 14;
    int r2  = idx & 16383;
    int g   = r2 >> 3;
    int e   = r2 & 7;
    int oc  = g >> 3;
    int kk8 = (g & 7) ^ (oc & 7);
    int kk  = kk8 * 8 + e;
    int c   = (t & 3) * 64 + kk;
    int k   = t >> 2;
    w3s[idx] = __builtin_bit_cast(unsigned short, __float2bfloat16(w[(oc * 256 + c) * 9 + k]));
  } else {
    // offsets -> packed coord entries {4 x f16 w, 4 x u16 pix}
    int idx = (blockIdx.x - 4352) * 256 + tid;   // < 294912
    int ow  = idx & 63;
    int oh  = (idx >> 6) & 63;
    int r   = idx >> 12;          // bn*9 + k
    int k   = r % 9;
    int bn  = r / 9;
    int ky = k / 3 - 1;
    int kx = k % 3 - 1;
    float offy = offset[((bn * 18 + 2 * k    ) * 64 + oh) * 64 + ow];
    float offx = offset[((bn * 18 + 2 * k + 1) * 64 + oh) * 64 + ow];
    float y = (float)(oh + ky) + offy;
    float x2 = (float)(ow + kx) + offx;
    float y0f = floorf(y), x0f = floorf(x2);
    float fy = y - y0f, fx = x2 - x0f;
    int y0 = (int)y0f, x0 = (int)x0f;
    int y1 = y0 + 1, x1 = x0 + 1;
    float vy0 = (y0 >= 0 && y0 <= 63) ? 1.0f : 0.0f;
    float vy1 = (y1 >= 0 && y1 <= 63) ? 1.0f : 0.0f;
    float vx0 = (x0 >= 0 && x0 <= 63) ? 1.0f : 0.0f;
    float vx1 = (x1 >= 0 && x1 <= 63) ? 1.0f : 0.0f;
    float wy0 = (1.0f - fy) * vy0, wy1 = fy * vy1;
    float wx0 = (1.0f - fx) * vx0, wx1 = fx * vx1;
    int y0c = min(max(y0, 0), 63), y1c = min(max(y1, 0), 63);
    int x0c = min(max(x0, 0), 63), x1c = min(max(x1, 0), 63);
    unsigned short ent[8];
    ent[0] = __builtin_bit_cast(unsigned short, __float2half(wy0 * wx0));
    ent[1] = __builtin_bit_cast(unsigned short, __float2half(wy0 * wx1));
    ent[2] = __builtin_bit_cast(unsigned short, __float2half(wy1 * wx0));
    ent[3] = __builtin_bit_cast(unsigned short, __float2half(wy1 * wx1));
    ent[4] = (unsigned short)(y0c * 64 + x0c);
    ent[5] = (unsigned short)(y0c * 64 + x1c);
    ent[6] = (unsigned short)(y1c * 64 + x0c);
    ent[7] = (unsigned short)(y1c * 64 + x1c);
    *(uint4*)(coords + (size_t)idx * 8) = *(const uint4*)ent;
  }
}

// ---- main: 512 blocks x 512 threads; block tile 64 rows x 256 oc; wave 32x64 ----
__global__ __launch_bounds__(512, 4) void deform_mfma_kernel(
    const unsigned short* __restrict__ xb,      // NHWC bf16
    const unsigned short* __restrict__ coords,  // packed coord entries
    const unsigned short* __restrict__ w3s,     // swizzled chunk-major bf16
    float* __restrict__ out) {                  // (8, 256, 64, 64) fp32
  __shared__ __align__(16) unsigned short At[64 * 72];   // 9216 B (single)
  __shared__ __align__(16) unsigned short Bt[256 * 64];  // 32768 B (single, swizzled)

  int bn  = blockIdx.x & 7;      // XCD swizzle
  int oh  = blockIdx.x >> 3;
  int tid = threadIdx.x;

  int w     = tid >> 6;            // wave 0..7
  int lane  = tid & 63;
  int wrow  = w & 1;               // row half (32 rows)
  int wcol  = w >> 1;              // oc quarter (64 oc)
  int mrow  = lane & 15;
  int quad  = lane >> 4;

  // staging identity: one thread = one (row, 8-ch group) unit
  int srow = tid >> 3;             // 0..63
  int sg   = tid & 7;              // channel group

  const unsigned short* xbn = xb + (size_t)bn * (64 * 64 * 256);
  const char* gbase = (const char*)xbn + sg * 16;            // + (s&3)*128 + pix*512
  const unsigned short* cbase = coords + ((size_t)((bn * 9) * 64 + oh) * 64 + srow) * 8;

  f32x4 acc[2][4] = {};

#define BDMA(TT)                                                                \
  {                                                                             \
    const unsigned short* src = w3s + (TT) * 16384;                             \
    _Pragma("unroll")                                                           \
    for (int j = 0; j < 4; ++j) {                                               \
      int base16 = j * 512 + w * 64;                                            \
      __builtin_amdgcn_global_load_lds(                                         \
          (const __attribute__((address_space(1))) void*)(src + (base16 + lane) * 8), \
          (__attribute__((address_space(3))) void*)(Bt + base16 * 8),           \
          16, 0, 0);                                                            \
    }                                                                           \
  }

  // issue 4 corner loads for chunk staged via entry EV, channel block CH
#define CLOAD(D00, D01, D10, D11, EV, CH)                                       \
  {                                                                             \
    const char* gb_ = gbase + (CH) * 128;                                       \
    D00 = *(const uint4*)(gb_ + (((EV).z & 0xffffu) << 9));                     \
    D01 = *(const uint4*)(gb_ + (((EV).z >> 16) << 9));                         \
    D10 = *(const uint4*)(gb_ + (((EV).w & 0xffffu) << 9));                     \
    D11 = *(const uint4*)(gb_ + (((EV).w >> 16) << 9));                         \
  }

  // interp from corner regs + packed weights WX/WY, write 16B to At
#define INTERP_WRITE(C00, C01, C10, C11, WX, WY)                                \
  {                                                                             \
    float w00 = h2f((WX) & 0xffffu), w01 = h2f((WX) >> 16);                     \
    float w10 = h2f((WY) & 0xffffu), w11 = h2f((WY) >> 16);                     \
    float a0 = bflo(C00.x) * w00 + bflo(C01.x) * w01 + bflo(C10.x) * w10 + bflo(C11.x) * w11; \
    float a1 = bfhi(C00.x) * w00 + bfhi(C01.x) * w01 + bfhi(C10.x) * w10 + bfhi(C11.x) * w11; \
    float a2 = bflo(C00.y) * w00 + bflo(C01.y) * w01 + bflo(C10.y) * w10 + bflo(C11.y) * w11; \
    float a3 = bfhi(C00.y) * w00 + bfhi(C01.y) * w01 + bfhi(C10.y) * w10 + bfhi(C11.y) * w11; \
    float a4 = bflo(C00.z) * w00 + bflo(C01.z) * w01 + bflo(C10.z) * w10 + bflo(C11.z) * w11; \
    float a5 = bfhi(C00.z) * w00 + bfhi(C01.z) * w01 + bfhi(C10.z) * w10 + bfhi(C11.z) * w11; \
    float a6 = bflo(C00.w) * w00 + bflo(C01.w) * w01 + bflo(C10.w) * w10 + bflo(C11.w) * w11; \
    float a7 = bfhi(C00.w) * w00 + bfhi(C01.w) * w01 + bfhi(C10.w) * w10 + bfhi(C11.w) * w11; \
    uint4 pk;                                                                   \
    pk.x = packbf(a0, a1); pk.y = packbf(a2, a3);                               \
    pk.z = packbf(a4, a5); pk.w = packbf(a6, a7);                               \
    *(uint4*)(&At[srow * 72 + sg * 8]) = pk;                                    \
  }

  // ---- prologue ----
  uint4 eR = *(const uint4*)(cbase);          // tap 0 entry
  {                                           // stage chunk 0 directly
    uint4 p00, p01, p10, p11;
    CLOAD(p00, p01, p10, p11, eR, 0)
    INTERP_WRITE(p00, p01, p10, p11, eR.x, eR.y)
  }
  BDMA(0)
  uint4 c00, c01, c10, c11;                   // corners for chunk t+1 (pipeline regs)
  uint32_t wx, wy;                            // their bilinear weights
  CLOAD(c00, c01, c10, c11, eR, 1)            // chunk 1, tap 0
  wx = eR.x; wy = eR.y;
  __syncthreads();

  short8 af[2][2];
  short8 bfr[2][4];

  for (int t = 0; t < 36; ++t) {
    // ---- phase 1: preload fragments for chunk t ----
#pragma unroll
    for (int ks = 0; ks < 2; ++ks) {
#pragma unroll
      for (int m = 0; m < 2; ++m)
        af[m][ks] = *(const short8*)(&At[(wrow * 32 + m * 16 + mrow) * 72 + ks * 32 + quad * 8]);
#pragma unroll
      for (int nn = 0; nn < 4; ++nn) {
        int oc  = wcol * 64 + nn * 16 + mrow;
        int g16 = oc * 8 + ((ks * 4 + quad) ^ (mrow & 7));
        bfr[ks][nn] = *(const short8*)(Bt + g16 * 8);
      }
    }
    __syncthreads();   // all At/Bt reads done -> safe to overwrite

    // ---- phase 2 ----
    if (t < 35) {
      BDMA(t + 1)                                    // earliest issue for drain cover
      INTERP_WRITE(c00, c01, c10, c11, wx, wy)       // chunk t+1 from prefetched regs
    }
    if (t <= 33) {                                   // prefetch corners for chunk t+2
      CLOAD(c00, c01, c10, c11, eR, ((t + 2) & 3))
      wx = eR.x; wy = eR.y;
    }
    if ((t & 3) == 1 && t <= 29)                     // e for next tap, 1 chunk ahead
      eR = *(const uint4*)(cbase + ((t + 6) >> 2) * 32768);

#pragma unroll
    for (int ks = 0; ks < 2; ++ks)
#pragma unroll
      for (int m = 0; m < 2; ++m)
#pragma unroll
        for (int nn = 0; nn < 4; ++nn)
          acc[m][nn] = __builtin_amdgcn_mfma_f32_16x16x32_bf16(af[m][ks], bfr[ks][nn], acc[m][nn], 0, 0, 0);
    __syncthreads();   // staging of t+1 complete before next preload
  }

  // ---- epilogue: C/D layout col=lane&15(oc), row=quad*4+reg(ow) ----
  float* outp = out + (size_t)(bn * 256) * 4096 + oh * 64;
#pragma unroll
  for (int m = 0; m < 2; ++m) {
    int ow0 = wrow * 32 + m * 16 + quad * 4;
#pragma unroll
    for (int nn = 0; nn < 4; ++nn) {
      int oc = wcol * 64 + nn * 16 + mrow;
      *(f32x4*)(outp + oc * 4096 + ow0) = acc[m][nn];
    }
  }
#undef BDMA
#undef CLOAD
#undef INTERP_WRITE
}

extern "C" void kernel_launch(void* const* d_in, const int* in_sizes, int n_in,
                              void* d_out, int out_size, void* d_ws, size_t ws_size,
                              hipStream_t stream) {
  (void)in_sizes; (void)n_in; (void)out_size; (void)ws_size;
  const float* x      = (const float*)d_in[0];
  const float* offset = (const float*)d_in[1];
  const float* weight = (const float*)d_in[2];
  float* out = (float*)d_out;

  unsigned short* xb     = (unsigned short*)d_ws;                        // 16.78 MB
  unsigned short* w3s    = xb + (size_t)8 * 64 * 64 * 256;               // +1.18 MB
  unsigned short* coords = w3s + (size_t)36 * 16384;                     // +4.72 MB

  prep_all_kernel<<<5504, 256, 0, stream>>>(x, weight, offset, xb, w3s, coords);
  deform_mfma_kernel<<<512, 512, 0, stream>>>(xb, coords, w3s, out);
}